// Round 13
// baseline (445.249 us; speedup 1.0000x reference)
//
#include <hip/hip_runtime.h>

#define N_NODES 50000
#define N_EDGES 800000
#define IN_DIM  128
#define EDGE_DIM 64
#define OUT_DIM 128
#define NODE_TILES ((N_NODES + 127) / 128)  // 391
#define W2_BLOCKS 32
#define CNT_BLOCKS ((N_EDGES + 255) / 256)  // 3125

typedef __attribute__((ext_vector_type(8))) short bf16x8;
typedef __attribute__((ext_vector_type(4))) short bf16x4;
typedef __attribute__((ext_vector_type(4))) float f32x4;
typedef unsigned short u16;

__device__ __forceinline__ u16 f2bf(float f) {
    union { float f; unsigned u; } x; x.f = f;
    unsigned r = x.u + 0x7FFFu + ((x.u >> 16) & 1u);
    return (u16)(r >> 16);
}
__device__ __forceinline__ float bf2f(u16 h) {
    union { unsigned u; float f; } x; x.u = ((unsigned)h) << 16;
    return x.f;
}
__device__ __forceinline__ bf16x8 pack8(const float* v) {
    bf16x8 r;
#pragma unroll
    for (int i = 0; i < 8; ++i) r[i] = (short)f2bf(v[i]);
    return r;
}

// ---------------------------------------------------------------------------
// prep_kernel (R12-verified): node GEMM -> H1,HS ; W2fT ; count/rank
// ---------------------------------------------------------------------------
__global__ __launch_bounds__(256, 1) void prep_kernel(
    const float* __restrict__ nfeat, const float* __restrict__ W_ne,
    const float* __restrict__ W_self, const float* __restrict__ b_self,
    const float* __restrict__ W_edge, const int* __restrict__ dst,
    u16* __restrict__ H1, u16* __restrict__ HS,
    float* __restrict__ W2fT, int* __restrict__ cnts, int* __restrict__ rank) {

    __shared__ __align__(16) char Nb[128 * 128 * 2];   // 32 KB bf16 tile

    const int bid = blockIdx.x;
    const int tid = threadIdx.x;

    if (bid >= NODE_TILES) {
        if (bid < NODE_TILES + W2_BLOCKS) {
            const int idx = (bid - NODE_TILES) * 256 + tid;
            const int c = idx >> 7;
            const int o = idx & 127;
            float acc = 0.0f;
            for (int i = 0; i < OUT_DIM; ++i)
                acc += W_edge[c * OUT_DIM + i] * W_ne[(IN_DIM + i) * OUT_DIM + o];
            W2fT[o * EDGE_DIM + c] = acc;
        } else {
            const int e = (bid - NODE_TILES - W2_BLOCKS) * 256 + tid;
            if (e < N_EDGES) rank[e] = atomicAdd(&cnts[dst[e]], 1);
        }
        return;
    }

    const int w    = tid >> 6;
    const int l    = tid & 63;
    const int lrow = l & 15;
    const int lq   = l >> 4;

    const bool isSelf = (w >= 2);
    const float* W = isSelf ? W_self : W_ne;   // rows [0,128) of W_ne == W1
    const int colw = (w & 1) * 64;
    u16* Y = isSelf ? HS : H1;

    bf16x8 Wf[4][4];
#pragma unroll
    for (int mt = 0; mt < 4; ++mt) {
        const int c = colw + mt * 16 + lrow;
#pragma unroll
        for (int kk = 0; kk < 4; ++kk) {
            float tmp[8];
#pragma unroll
            for (int t = 0; t < 8; ++t) tmp[t] = W[(kk * 32 + lq * 8 + t) * 128 + c];
            Wf[mt][kk] = pack8(tmp);
        }
    }
    float4 bias4[4];
#pragma unroll
    for (int mt = 0; mt < 4; ++mt) {
        if (isSelf) bias4[mt] = *(const float4*)(b_self + colw + mt * 16 + lq * 4);
        else { bias4[mt].x = 0.f; bias4[mt].y = 0.f; bias4[mt].z = 0.f; bias4[mt].w = 0.f; }
    }

    const int srow = tid >> 1;
    const int skc  = (tid & 1) * 8;
    const int r0 = bid * 128;
    {
        const int gr = min(r0 + srow, N_NODES - 1);
        const float4* np = (const float4*)(nfeat + (size_t)gr * 128 + skc * 8);
        const int swz = (srow & 7);
#pragma unroll
        for (int j = 0; j < 8; ++j) {
            float4 x = np[2 * j], y = np[2 * j + 1];
            float tmp[8] = {x.x, x.y, x.z, x.w, y.x, y.y, y.z, y.w};
            bf16x8 f = pack8(tmp);
            const int kc = skc + j;
            *(bf16x8*)(Nb + srow * 256 + (((kc) ^ swz) * 16)) = f;
        }
    }
    __syncthreads();

    f32x4 acc[4][8];
#pragma unroll
    for (int mt = 0; mt < 4; ++mt)
#pragma unroll
        for (int nt = 0; nt < 8; ++nt) {
            acc[mt][nt][0] = bias4[mt].x; acc[mt][nt][1] = bias4[mt].y;
            acc[mt][nt][2] = bias4[mt].z; acc[mt][nt][3] = bias4[mt].w;
        }
#pragma unroll
    for (int nt = 0; nt < 8; ++nt) {
        const int r = nt * 16 + lrow;
        const int swz = (r & 7);
        bf16x8 Be[4];
#pragma unroll
        for (int kk = 0; kk < 4; ++kk)
            Be[kk] = *(const bf16x8*)(Nb + r * 256 + (((kk * 4 + lq) ^ swz) * 16));
#pragma unroll
        for (int mt = 0; mt < 4; ++mt)
#pragma unroll
            for (int kk = 0; kk < 4; ++kk)
                acc[mt][nt] = __builtin_amdgcn_mfma_f32_16x16x32_bf16(Wf[mt][kk], Be[kk], acc[mt][nt], 0, 0, 0);
    }

#pragma unroll
    for (int nt = 0; nt < 8; ++nt) {
        const int n = r0 + nt * 16 + lrow;
        if (n < N_NODES) {
#pragma unroll
            for (int mt = 0; mt < 4; ++mt) {
                const int c0 = colw + mt * 16 + lq * 4;
                ushort4 o;
                o.x = f2bf(acc[mt][nt][0]); o.y = f2bf(acc[mt][nt][1]);
                o.z = f2bf(acc[mt][nt][2]); o.w = f2bf(acc[mt][nt][3]);
                *(ushort4*)(Y + (size_t)n * 128 + c0) = o;
            }
        }
    }
}

// ---------------------------------------------------------------------------
#define SCAN_T 1024
#define SCAN_CHUNK 49
__global__ void scan_kernel(const int* __restrict__ counts, int* __restrict__ off) {
    __shared__ int part[SCAN_T];
    const int t = threadIdx.x;
    const int base = t * SCAN_CHUNK;
    int s = 0;
    for (int k = 0; k < SCAN_CHUNK; ++k) {
        const int i = base + k;
        if (i < N_NODES) s += counts[i];
    }
    part[t] = s;
    __syncthreads();
    for (int d = 1; d < SCAN_T; d <<= 1) {
        int v = (t >= d) ? part[t - d] : 0;
        __syncthreads();
        part[t] += v;
        __syncthreads();
    }
    int excl = part[t] - s;
    for (int k = 0; k < SCAN_CHUNK; ++k) {
        const int i = base + k;
        if (i < N_NODES) { off[i] = excl; excl += counts[i]; }
    }
    if (t == SCAN_T - 1) off[N_NODES] = excl;
}

__global__ void scatter_kernel(const int* __restrict__ dst, const int* __restrict__ src,
                               const int* __restrict__ rank, const int* __restrict__ off,
                               int* __restrict__ eidS, int* __restrict__ srcS) {
    const int e = blockIdx.x * blockDim.x + threadIdx.x;
    if (e < N_EDGES) {
        const int slot = off[dst[e]] + rank[e];
        eidS[slot] = e;
        srcS[slot] = src[e];
    }
}

// ---------------------------------------------------------------------------
// FUSED wave-per-node kernel (no block barriers, per-wave LDS slices):
// per 16-edge pass:
//   - 16-lane groups gather efeat rows (256B fp32) -> bf16 A-slice (swz 16B)
//   - 16-lane groups gather H1[src] rows (256B bf16) -> H-slice (swz 8B)
//   - MFMA 16x128xK64 (normal orientation, R2-verified fragments)
//   - v = relu(E2 + H1 + b), masked by slot validity, f32 nodeSum[8]
// finalize: shfl_xor(16,32) col-reduce, /max(deg,1), +HS, float2 store.
// ---------------------------------------------------------------------------
__global__ __launch_bounds__(256, 2) void fused_node_kernel(
    const float* __restrict__ efeat, const int* __restrict__ eidS,
    const int* __restrict__ srcS, const int* __restrict__ offs,
    const float* __restrict__ W2fT, const float* __restrict__ b_ne,
    const u16* __restrict__ H1, const u16* __restrict__ HS,
    float* __restrict__ out) {

    __shared__ __align__(16) char LA[4][16 * 128];   // per-wave A: 16 rows x 64 bf16
    __shared__ __align__(16) char LH[4][16 * 256];   // per-wave H: 16 rows x 128 bf16

    const int tid  = threadIdx.x;
    const int w    = tid >> 6;
    const int l    = tid & 63;
    const int lrow = l & 15;
    const int lq   = l >> 4;
    const int gi   = lrow;      // lane within gather group (group id = lq)

    char* A = LA[w];
    char* H = LH[w];

    // B fragments + bias (R2-verified layout)
    bf16x8 Bf[8][2];
    float bias[8];
#pragma unroll
    for (int nt = 0; nt < 8; ++nt) {
        bias[nt] = b_ne[nt * 16 + lrow];
#pragma unroll
        for (int kk = 0; kk < 2; ++kk) {
            const float* wp = W2fT + (nt * 16 + lrow) * 64 + kk * 32 + lq * 8;
            float tmp[8];
#pragma unroll
            for (int j = 0; j < 8; ++j) tmp[j] = wp[j];
            Bf[nt][kk] = pack8(tmp);
        }
    }

    const int n = blockIdx.x * 4 + w;
    if (n >= N_NODES) return;    // safe: no barriers in this kernel
    const int s0 = offs[n], s1 = offs[n + 1];
    const int deg = s1 - s0;

    float nodeSum[8];
#pragma unroll
    for (int nt = 0; nt < 8; ++nt) nodeSum[nt] = 0.0f;

    const int npass = (deg + 15) >> 4;
    for (int p = 0; p < npass; ++p) {
        const int base = s0 + p * 16;

        // ---- gather: group lq loads rows lq*4+it (efeat 256B fp32, H1 256B bf16)
#pragma unroll
        for (int it = 0; it < 4; ++it) {
            const int r = lq * 4 + it;
            int slot = base + r;
            if (slot >= s1) slot = s1 - 1;          // clamp; masked later
            const int e  = eidS[slot];               // uniform across group
            const int sc = srcS[slot];

            float4 f4 = *(const float4*)(efeat + (size_t)e * 64 + gi * 4);
            ushort4 a4;
            a4.x = f2bf(f4.x); a4.y = f2bf(f4.y); a4.z = f2bf(f4.z); a4.w = f2bf(f4.w);
            *(ushort4*)(A + r * 128 + ((gi * 8) ^ ((r & 7) << 4))) = a4;

            bf16x8 hv = *(const bf16x8*)(H1 + (size_t)sc * 128 + gi * 8);
            const int hs8 = (r & 7) << 3;
            *(bf16x4*)(H + r * 256 + ((gi * 16) ^ hs8))     = *(((const bf16x4*)&hv));
            *(bf16x4*)(H + r * 256 + ((gi * 16 + 8) ^ hs8)) = *(((const bf16x4*)&hv) + 1);
        }

        // ---- MFMA: A-frag row=lrow, k=kk*32+lq*8 (R2-verified)
        bf16x8 Af[2];
#pragma unroll
        for (int kk = 0; kk < 2; ++kk)
            Af[kk] = *(const bf16x8*)(A + lrow * 128 + ((kk * 64 + lq * 16) ^ ((lrow & 7) << 4)));

        f32x4 acc[8];
#pragma unroll
        for (int nt = 0; nt < 8; ++nt) {
            acc[nt][0] = bias[nt]; acc[nt][1] = bias[nt];
            acc[nt][2] = bias[nt]; acc[nt][3] = bias[nt];
            acc[nt] = __builtin_amdgcn_mfma_f32_16x16x32_bf16(Af[0], Bf[nt][0], acc[nt], 0, 0, 0);
            acc[nt] = __builtin_amdgcn_mfma_f32_16x16x32_bf16(Af[1], Bf[nt][1], acc[nt], 0, 0, 0);
        }

        // ---- epilogue: v = relu(acc + H1[row][col]), masked accumulate
        const int remain = deg - p * 16;
#pragma unroll
        for (int j = 0; j < 4; ++j) {
            const int row = lq * 4 + j;
            const bool valid = row < remain;
            const int hs8 = (row & 7) << 3;
#pragma unroll
            for (int nt = 0; nt < 8; ++nt) {
                const int col = nt * 16 + lrow;
                const u16 h = *(const u16*)(H + row * 256 + ((col * 2) ^ hs8));
                float v = fmaxf(acc[nt][j] + bf2f(h), 0.0f);
                if (valid) nodeSum[nt] += v;
            }
        }
    }

    // ---- cross-lane reduce over lq (rows) -> full col sums on every lane
#pragma unroll
    for (int nt = 0; nt < 8; ++nt) {
        nodeSum[nt] += __shfl_xor(nodeSum[nt], 16, 64);
        nodeSum[nt] += __shfl_xor(nodeSum[nt], 32, 64);
    }

    // ---- finalize: park col sums (f32) in A-slice, then coalesced out write
    const float inv = (deg > 0) ? 1.0f / (float)deg : 0.0f;
    if (lq == 0) {
#pragma unroll
        for (int nt = 0; nt < 8; ++nt)
            *(float*)(A + (nt * 16 + lrow) * 4) = nodeSum[nt] * inv;
    }
    // same wave: compiler inserts lgkmcnt wait on the LDS dependency
    float2 r2 = *(const float2*)(A + l * 8);
    const unsigned hs2 = *(const unsigned*)(HS + (size_t)n * 128 + l * 2);
    float2 o2;
    o2.x = r2.x + bf2f((u16)(hs2 & 0xffff));
    o2.y = r2.y + bf2f((u16)(hs2 >> 16));
    *(float2*)(out + (size_t)n * 128 + l * 2) = o2;
}

// ---------------------------------------------------------------------------
extern "C" void kernel_launch(void* const* d_in, const int* in_sizes, int n_in,
                              void* d_out, int out_size, void* d_ws, size_t ws_size,
                              hipStream_t stream) {
    const float* nfeat  = (const float*)d_in[0];
    const float* efeat  = (const float*)d_in[1];
    const int*   src    = (const int*)d_in[2];
    const int*   dst    = (const int*)d_in[3];
    const float* W_edge = (const float*)d_in[4];
    const float* W_ne   = (const float*)d_in[5];
    const float* b_ne   = (const float*)d_in[6];
    const float* W_self = (const float*)d_in[7];
    const float* b_self = (const float*)d_in[8];

    float* out = (float*)d_out;
    char* ws = (char*)d_ws;

    // ws layout (~36 MB)
    const size_t OFF_W2   = 0;          // 32768 B
    const size_t OFF_CNT  = 32768;      // 200192 B (padded)
    const size_t OFF_OFFS = 232960;     // 200448 B (padded, N+1 ints)
    const size_t OFF_RANK = 433408;     // 3.2 MB
    const size_t OFF_EID  = 3633408;    // 3.2 MB
    const size_t OFF_SRCS = 6833408;    // 3.2 MB
    const size_t OFF_H1   = 10033408;   // 12.8 MB
    const size_t OFF_HS   = 22833408;   // 12.8 MB -> end 35633408

    float* W2fT = (float*)(ws + OFF_W2);
    int*   cnts = (int*)(ws + OFF_CNT);
    int*   offs = (int*)(ws + OFF_OFFS);
    int*   rank = (int*)(ws + OFF_RANK);
    int*   eidS = (int*)(ws + OFF_EID);
    int*   srcS = (int*)(ws + OFF_SRCS);
    u16*   H1   = (u16*)(ws + OFF_H1);
    u16*   HS   = (u16*)(ws + OFF_HS);

    hipMemsetAsync(cnts, 0, N_NODES * sizeof(int), stream);
    prep_kernel<<<NODE_TILES + W2_BLOCKS + CNT_BLOCKS, 256, 0, stream>>>(
        nfeat, W_ne, W_self, b_self, W_edge, dst, H1, HS, W2fT, cnts, rank);
    scan_kernel<<<1, SCAN_T, 0, stream>>>(cnts, offs);
    scatter_kernel<<<(N_EDGES + 255) / 256, 256, 0, stream>>>(dst, src, rank, offs, eidS, srcS);
    fused_node_kernel<<<(N_NODES + 3) / 4, 256, 0, stream>>>(
        efeat, eidS, srcS, offs, W2fT, b_ne, H1, HS, out);
}

// Round 14
// 300.950 us; speedup vs baseline: 1.4795x; 1.4795x over previous
//
#include <hip/hip_runtime.h>

#define N_NODES 50000
#define N_EDGES 800000
#define IN_DIM  128
#define EDGE_DIM 64
#define OUT_DIM 128
#define NTILES  (N_EDGES / 128)             // 6250 exact
#define NODE_TILES ((N_NODES + 127) / 128)  // 391
#define W2_BLOCKS 32
#define CNT_BLOCKS ((N_EDGES + 255) / 256)  // 3125

typedef __attribute__((ext_vector_type(8))) short bf16x8;
typedef __attribute__((ext_vector_type(4))) float f32x4;
typedef unsigned short u16;

__device__ __forceinline__ u16 f2bf(float f) {
    union { float f; unsigned u; } x; x.f = f;
    unsigned r = x.u + 0x7FFFu + ((x.u >> 16) & 1u);
    return (u16)(r >> 16);
}
__device__ __forceinline__ float bf2f(u16 h) {
    union { unsigned u; float f; } x; x.u = ((unsigned)h) << 16;
    return x.f;
}
__device__ __forceinline__ bf16x8 pack8(const float* v) {
    bf16x8 r;
#pragma unroll
    for (int i = 0; i < 8; ++i) r[i] = (short)f2bf(v[i]);
    return r;
}
// swizzled byte offset into a [128 rows][128 u16] LDS tile; chunk = u16col/4
__device__ __forceinline__ int hswz(int r, int chunk) {
    return r * 256 + ((chunk ^ ((((r & 7) ^ ((r >> 3) & 7))) << 2)) * 8);
}

// ---------------------------------------------------------------------------
// prep_kernel (R12-verified): node GEMM -> H1,HS ; W2fT ; count/rank
// ---------------------------------------------------------------------------
__global__ __launch_bounds__(256, 1) void prep_kernel(
    const float* __restrict__ nfeat, const float* __restrict__ W_ne,
    const float* __restrict__ W_self, const float* __restrict__ b_self,
    const float* __restrict__ W_edge, const int* __restrict__ dst,
    u16* __restrict__ H1, u16* __restrict__ HS,
    float* __restrict__ W2fT, int* __restrict__ cnts, int* __restrict__ rank) {

    __shared__ __align__(16) char Nb[128 * 128 * 2];   // 32 KB bf16 tile

    const int bid = blockIdx.x;
    const int tid = threadIdx.x;

    if (bid >= NODE_TILES) {
        if (bid < NODE_TILES + W2_BLOCKS) {
            const int idx = (bid - NODE_TILES) * 256 + tid;
            const int c = idx >> 7;
            const int o = idx & 127;
            float acc = 0.0f;
            for (int i = 0; i < OUT_DIM; ++i)
                acc += W_edge[c * OUT_DIM + i] * W_ne[(IN_DIM + i) * OUT_DIM + o];
            W2fT[o * EDGE_DIM + c] = acc;
        } else {
            const int e = (bid - NODE_TILES - W2_BLOCKS) * 256 + tid;
            if (e < N_EDGES) rank[e] = atomicAdd(&cnts[dst[e]], 1);
        }
        return;
    }

    const int w    = tid >> 6;
    const int l    = tid & 63;
    const int lrow = l & 15;
    const int lq   = l >> 4;

    const bool isSelf = (w >= 2);
    const float* W = isSelf ? W_self : W_ne;   // rows [0,128) of W_ne == W1
    const int colw = (w & 1) * 64;
    u16* Y = isSelf ? HS : H1;

    bf16x8 Wf[4][4];
#pragma unroll
    for (int mt = 0; mt < 4; ++mt) {
        const int c = colw + mt * 16 + lrow;
#pragma unroll
        for (int kk = 0; kk < 4; ++kk) {
            float tmp[8];
#pragma unroll
            for (int t = 0; t < 8; ++t) tmp[t] = W[(kk * 32 + lq * 8 + t) * 128 + c];
            Wf[mt][kk] = pack8(tmp);
        }
    }
    float4 bias4[4];
#pragma unroll
    for (int mt = 0; mt < 4; ++mt) {
        if (isSelf) bias4[mt] = *(const float4*)(b_self + colw + mt * 16 + lq * 4);
        else { bias4[mt].x = 0.f; bias4[mt].y = 0.f; bias4[mt].z = 0.f; bias4[mt].w = 0.f; }
    }

    const int srow = tid >> 1;
    const int skc  = (tid & 1) * 8;
    const int r0 = bid * 128;
    {
        const int gr = min(r0 + srow, N_NODES - 1);
        const float4* np = (const float4*)(nfeat + (size_t)gr * 128 + skc * 8);
        const int swz = (srow & 7);
#pragma unroll
        for (int j = 0; j < 8; ++j) {
            float4 x = np[2 * j], y = np[2 * j + 1];
            float tmp[8] = {x.x, x.y, x.z, x.w, y.x, y.y, y.z, y.w};
            bf16x8 f = pack8(tmp);
            const int kc = skc + j;
            *(bf16x8*)(Nb + srow * 256 + (((kc) ^ swz) * 16)) = f;
        }
    }
    __syncthreads();

    f32x4 acc[4][8];
#pragma unroll
    for (int mt = 0; mt < 4; ++mt)
#pragma unroll
        for (int nt = 0; nt < 8; ++nt) {
            acc[mt][nt][0] = bias4[mt].x; acc[mt][nt][1] = bias4[mt].y;
            acc[mt][nt][2] = bias4[mt].z; acc[mt][nt][3] = bias4[mt].w;
        }
#pragma unroll
    for (int nt = 0; nt < 8; ++nt) {
        const int r = nt * 16 + lrow;
        const int swz = (r & 7);
        bf16x8 Be[4];
#pragma unroll
        for (int kk = 0; kk < 4; ++kk)
            Be[kk] = *(const bf16x8*)(Nb + r * 256 + (((kk * 4 + lq) ^ swz) * 16));
#pragma unroll
        for (int mt = 0; mt < 4; ++mt)
#pragma unroll
            for (int kk = 0; kk < 4; ++kk)
                acc[mt][nt] = __builtin_amdgcn_mfma_f32_16x16x32_bf16(Wf[mt][kk], Be[kk], acc[mt][nt], 0, 0, 0);
    }

#pragma unroll
    for (int nt = 0; nt < 8; ++nt) {
        const int n = r0 + nt * 16 + lrow;
        if (n < N_NODES) {
#pragma unroll
            for (int mt = 0; mt < 4; ++mt) {
                const int c0 = colw + mt * 16 + lq * 4;
                ushort4 o;
                o.x = f2bf(acc[mt][nt][0]); o.y = f2bf(acc[mt][nt][1]);
                o.z = f2bf(acc[mt][nt][2]); o.w = f2bf(acc[mt][nt][3]);
                *(ushort4*)(Y + (size_t)n * 128 + c0) = o;
            }
        }
    }
}

// ---------------------------------------------------------------------------
#define SCAN_T 1024
#define SCAN_CHUNK 49
__global__ void scan_kernel(const int* __restrict__ counts, int* __restrict__ off) {
    __shared__ int part[SCAN_T];
    const int t = threadIdx.x;
    const int base = t * SCAN_CHUNK;
    int s = 0;
    for (int k = 0; k < SCAN_CHUNK; ++k) {
        const int i = base + k;
        if (i < N_NODES) s += counts[i];
    }
    part[t] = s;
    __syncthreads();
    for (int d = 1; d < SCAN_T; d <<= 1) {
        int v = (t >= d) ? part[t - d] : 0;
        __syncthreads();
        part[t] += v;
        __syncthreads();
    }
    int excl = part[t] - s;
    for (int k = 0; k < SCAN_CHUNK; ++k) {
        const int i = base + k;
        if (i < N_NODES) { off[i] = excl; excl += counts[i]; }
    }
    if (t == SCAN_T - 1) off[N_NODES] = excl;
}

// ---------------------------------------------------------------------------
// Edge GEMM v3 (R12-verified): all random global traffic in 128-B segments.
// ---------------------------------------------------------------------------
__global__ __launch_bounds__(256, 3) void edge_gemm_scatter_kernel(
    const float* __restrict__ efeat, const int* __restrict__ src,
    const int* __restrict__ dst, const int* __restrict__ rank,
    const int* __restrict__ offs, const float* __restrict__ W2fT,
    const float* __restrict__ b_ne, const u16* __restrict__ H1,
    u16* __restrict__ mbuf) {

    __shared__ __align__(16) char Ab[128 * 64 * 2];    // 16 KB A-tile
    __shared__ __align__(16) char HMb[128 * 128 * 2];  // 32 KB H1/m tile (swizzled)
    __shared__ int sS[128];
    __shared__ int sT[128];

    const int tid  = threadIdx.x;
    const int w    = tid >> 6;
    const int l    = tid & 63;
    const int lrow = l & 15;
    const int lq   = l >> 4;
    const int g    = tid >> 4;     // 16-lane group id (0..15)
    const int gi   = tid & 15;     // lane within group

    bf16x8 Wf[2][2];
    float4 bias4[2];
#pragma unroll
    for (int mt = 0; mt < 2; ++mt) {
        const int c = w * 32 + mt * 16 + lrow;
#pragma unroll
        for (int kk = 0; kk < 2; ++kk) {
            const float* wp = W2fT + c * 64 + kk * 32 + lq * 8;
            float tmp[8];
#pragma unroll
            for (int j = 0; j < 8; ++j) tmp[j] = wp[j];
            Wf[mt][kk] = pack8(tmp);
        }
        bias4[mt] = *(const float4*)(b_ne + w * 32 + mt * 16 + lq * 4);
    }

    const int srow = tid >> 1;
    const int skh  = (tid & 1) * 32;   // k-half in floats

    for (int tile = blockIdx.x; tile < NTILES; tile += gridDim.x) {
        const int e0 = tile * 128;

        if (tid < 128) {
            const int e = e0 + tid;
            sS[tid] = src[e];
            sT[tid] = offs[dst[e]] + rank[e];
        }
        // ---- stage efeat rows (sequential) -> bf16 swizzled LDS
        {
            const float4* ep = (const float4*)(efeat + (size_t)(e0 + srow) * 64 + skh);
            const int swz = (srow & 7) << 4;
#pragma unroll
            for (int j = 0; j < 4; ++j) {
                float4 x = ep[2 * j], y = ep[2 * j + 1];
                float tmp[8] = {x.x, x.y, x.z, x.w, y.x, y.y, y.z, y.w};
                bf16x8 f = pack8(tmp);
                *(bf16x8*)(Ab + ((srow * 128 + skh * 2 + j * 16) ^ swz)) = f;
            }
        }
        __syncthreads();   // B1: Ab, sS, sT ready; prev-tile HMb consumers done

        // ---- issue H1 gather (256B-contiguous per row; latency hides under MFMA)
        bf16x8 hreg[8];
#pragma unroll
        for (int k = 0; k < 8; ++k) {
            const int r = g * 8 + k;
            hreg[k] = *(const bf16x8*)(H1 + (size_t)sS[r] * 128 + gi * 8);
        }

        // ---- MFMA: D[out-col][edge] = W2f^T . efeat^T
        f32x4 acc[2][8];
#pragma unroll
        for (int mt = 0; mt < 2; ++mt)
#pragma unroll
            for (int nt = 0; nt < 8; ++nt) {
                acc[mt][nt][0] = bias4[mt].x; acc[mt][nt][1] = bias4[mt].y;
                acc[mt][nt][2] = bias4[mt].z; acc[mt][nt][3] = bias4[mt].w;
            }
#pragma unroll
        for (int nt = 0; nt < 8; ++nt) {
            const int r = nt * 16 + lrow;
            const int swz = (r & 7) << 4;
            bf16x8 Be0 = *(const bf16x8*)(Ab + ((r * 128 + lq * 16) ^ swz));
            bf16x8 Be1 = *(const bf16x8*)(Ab + ((r * 128 + 64 + lq * 16) ^ swz));
#pragma unroll
            for (int mt = 0; mt < 2; ++mt) {
                acc[mt][nt] = __builtin_amdgcn_mfma_f32_16x16x32_bf16(Wf[mt][0], Be0, acc[mt][nt], 0, 0, 0);
                acc[mt][nt] = __builtin_amdgcn_mfma_f32_16x16x32_bf16(Wf[mt][1], Be1, acc[mt][nt], 0, 0, 0);
            }
        }

        // ---- park gathered H1 rows into swizzled HMb
#pragma unroll
        for (int k = 0; k < 8; ++k) {
            const int r = g * 8 + k;
            *(bf16x8*)(HMb + hswz(r, 2 * gi)) = hreg[k];
        }
        __syncthreads();   // B2: HMb holds H1 rows

        // ---- epilogue: v = relu(acc + H1) written back in place
#pragma unroll
        for (int nt = 0; nt < 8; ++nt) {
            const int e = nt * 16 + lrow;
#pragma unroll
            for (int mt = 0; mt < 2; ++mt) {
                const int c0 = w * 32 + mt * 16 + lq * 4;
                const int byte = hswz(e, c0 >> 2);
                ushort4 h4 = *(const ushort4*)(HMb + byte);
                ushort4 o;
                o.x = f2bf(fmaxf(acc[mt][nt][0] + bf2f(h4.x), 0.0f));
                o.y = f2bf(fmaxf(acc[mt][nt][1] + bf2f(h4.y), 0.0f));
                o.z = f2bf(fmaxf(acc[mt][nt][2] + bf2f(h4.z), 0.0f));
                o.w = f2bf(fmaxf(acc[mt][nt][3] + bf2f(h4.w), 0.0f));
                *(ushort4*)(HMb + byte) = o;
            }
        }
        __syncthreads();   // B3: HMb holds m rows

        // ---- coalesced scatter: 16-lane groups write 256B-contiguous rows
#pragma unroll
        for (int k = 0; k < 8; ++k) {
            const int r  = g * 8 + k;
            const int st = sT[r];
            bf16x8 v = *(const bf16x8*)(HMb + hswz(r, 2 * gi));
            *(bf16x8*)(mbuf + (size_t)st * 128 + gi * 8) = v;
        }
        // B1 of next iteration protects HMb reuse
    }
}

// ---------------------------------------------------------------------------
// Reduce v3: 16-lane group per node (4 nodes/wave).
//   Group reads its node's rows WHOLE (16 lanes x 16B = 256B per row, one
//   request per row); lane gi owns cols gi*8..+8 across all rows -> no
//   cross-lane reduce. Store: 512B coalesced per node.
// ---------------------------------------------------------------------------
__global__ __launch_bounds__(256, 4) void reduce_kernel(
    const int* __restrict__ off, const u16* __restrict__ mbuf,
    const u16* __restrict__ HS, float* __restrict__ out) {
    const int n  = (blockIdx.x * blockDim.x + threadIdx.x) >> 4;  // group = node
    if (n >= N_NODES) return;
    const int gi = threadIdx.x & 15;
    const int s0 = off[n], s1 = off[n + 1];

    float facc[8];
#pragma unroll
    for (int i = 0; i < 8; ++i) facc[i] = 0.0f;

    int s = s0;
    // 4 rows in flight (independent addresses -> MLP)
    for (; s + 4 <= s1; s += 4) {
        bf16x8 v0 = *(const bf16x8*)(mbuf + (size_t)(s + 0) * 128 + gi * 8);
        bf16x8 v1 = *(const bf16x8*)(mbuf + (size_t)(s + 1) * 128 + gi * 8);
        bf16x8 v2 = *(const bf16x8*)(mbuf + (size_t)(s + 2) * 128 + gi * 8);
        bf16x8 v3 = *(const bf16x8*)(mbuf + (size_t)(s + 3) * 128 + gi * 8);
#pragma unroll
        for (int i = 0; i < 8; ++i)
            facc[i] += (bf2f((u16)v0[i]) + bf2f((u16)v1[i])) +
                       (bf2f((u16)v2[i]) + bf2f((u16)v3[i]));
    }
    for (; s < s1; ++s) {
        bf16x8 v = *(const bf16x8*)(mbuf + (size_t)s * 128 + gi * 8);
#pragma unroll
        for (int i = 0; i < 8; ++i) facc[i] += bf2f((u16)v[i]);
    }

    const int c = s1 - s0;
    const float inv = (c > 0) ? 1.0f / (float)c : 0.0f;
    bf16x8 hs = *(const bf16x8*)(HS + (size_t)n * 128 + gi * 8);
    float* op = out + (size_t)n * 128 + gi * 8;
    float4 o0, o1;
    o0.x = facc[0] * inv + bf2f((u16)hs[0]);
    o0.y = facc[1] * inv + bf2f((u16)hs[1]);
    o0.z = facc[2] * inv + bf2f((u16)hs[2]);
    o0.w = facc[3] * inv + bf2f((u16)hs[3]);
    o1.x = facc[4] * inv + bf2f((u16)hs[4]);
    o1.y = facc[5] * inv + bf2f((u16)hs[5]);
    o1.z = facc[6] * inv + bf2f((u16)hs[6]);
    o1.w = facc[7] * inv + bf2f((u16)hs[7]);
    *(float4*)op = o0;
    *(float4*)(op + 4) = o1;
}

// ---------------------------------------------------------------------------
extern "C" void kernel_launch(void* const* d_in, const int* in_sizes, int n_in,
                              void* d_out, int out_size, void* d_ws, size_t ws_size,
                              hipStream_t stream) {
    const float* nfeat  = (const float*)d_in[0];
    const float* efeat  = (const float*)d_in[1];
    const int*   src    = (const int*)d_in[2];
    const int*   dst    = (const int*)d_in[3];
    const float* W_edge = (const float*)d_in[4];
    const float* W_ne   = (const float*)d_in[5];
    const float* b_ne   = (const float*)d_in[6];
    const float* W_self = (const float*)d_in[7];
    const float* b_self = (const float*)d_in[8];

    float* out = (float*)d_out;
    char* ws = (char*)d_ws;

    // ws layout (~234.1 MB; >=237 MB proven available)
    const size_t OFF_W2   = 0;          // 32768 B
    const size_t OFF_CNT  = 32768;      // 200000 B (+pad)
    const size_t OFF_OFFS = 232960;     // 200064 B (+pad)
    const size_t OFF_RANK = 433152;     // 3.2 MB
    const size_t OFF_H1   = 3633152;    // 12.8 MB
    const size_t OFF_HS   = 16433152;   // 12.8 MB
    const size_t OFF_M    = 29233152;   // 204.8 MB -> end 234033152

    float* W2fT = (float*)(ws + OFF_W2);
    int*   cnts = (int*)(ws + OFF_CNT);
    int*   offs = (int*)(ws + OFF_OFFS);
    int*   rank = (int*)(ws + OFF_RANK);
    u16*   H1   = (u16*)(ws + OFF_H1);
    u16*   HS   = (u16*)(ws + OFF_HS);
    u16*   mbuf = (u16*)(ws + OFF_M);

    hipMemsetAsync(cnts, 0, N_NODES * sizeof(int), stream);
    prep_kernel<<<NODE_TILES + W2_BLOCKS + CNT_BLOCKS, 256, 0, stream>>>(
        nfeat, W_ne, W_self, b_self, W_edge, dst, H1, HS, W2fT, cnts, rank);
    scan_kernel<<<1, SCAN_T, 0, stream>>>(cnts, offs);
    edge_gemm_scatter_kernel<<<2048, 256, 0, stream>>>(
        efeat, src, dst, rank, offs, W2fT, b_ne, H1, mbuf);
    reduce_kernel<<<(N_NODES * 16 + 255) / 256, 256, 0, stream>>>(offs, mbuf, HS, out);
}

// Round 15
// 299.685 us; speedup vs baseline: 1.4857x; 1.0042x over previous
//
#include <hip/hip_runtime.h>

#define N_NODES 50000
#define N_EDGES 800000
#define IN_DIM  128
#define EDGE_DIM 64
#define OUT_DIM 128
#define NTILES  (N_EDGES / 128)             // 6250 exact
#define NODE_TILES ((N_NODES + 127) / 128)  // 391
#define W2_BLOCKS 32
#define CNT_BLOCKS ((N_EDGES + 255) / 256)  // 3125
#define HROW 272                            // HMb row stride (bytes): 16B-aligned,
                                            // phase step 4 banks/row -> conflict-free

typedef __attribute__((ext_vector_type(8))) short bf16x8;
typedef __attribute__((ext_vector_type(4))) float f32x4;
typedef unsigned short u16;

__device__ __forceinline__ u16 f2bf(float f) {
    union { float f; unsigned u; } x; x.f = f;
    unsigned r = x.u + 0x7FFFu + ((x.u >> 16) & 1u);
    return (u16)(r >> 16);
}
__device__ __forceinline__ float bf2f(u16 h) {
    union { unsigned u; float f; } x; x.u = ((unsigned)h) << 16;
    return x.f;
}
__device__ __forceinline__ bf16x8 pack8(const float* v) {
    bf16x8 r;
#pragma unroll
    for (int i = 0; i < 8; ++i) r[i] = (short)f2bf(v[i]);
    return r;
}

// ---------------------------------------------------------------------------
// prep_kernel (R12-verified): node GEMM -> H1,HS ; W2fT ; count/rank
// ---------------------------------------------------------------------------
__global__ __launch_bounds__(256, 1) void prep_kernel(
    const float* __restrict__ nfeat, const float* __restrict__ W_ne,
    const float* __restrict__ W_self, const float* __restrict__ b_self,
    const float* __restrict__ W_edge, const int* __restrict__ dst,
    u16* __restrict__ H1, u16* __restrict__ HS,
    float* __restrict__ W2fT, int* __restrict__ cnts, int* __restrict__ rank) {

    __shared__ __align__(16) char Nb[128 * 128 * 2];   // 32 KB bf16 tile

    const int bid = blockIdx.x;
    const int tid = threadIdx.x;

    if (bid >= NODE_TILES) {
        if (bid < NODE_TILES + W2_BLOCKS) {
            const int idx = (bid - NODE_TILES) * 256 + tid;
            const int c = idx >> 7;
            const int o = idx & 127;
            float acc = 0.0f;
            for (int i = 0; i < OUT_DIM; ++i)
                acc += W_edge[c * OUT_DIM + i] * W_ne[(IN_DIM + i) * OUT_DIM + o];
            W2fT[o * EDGE_DIM + c] = acc;
        } else {
            const int e = (bid - NODE_TILES - W2_BLOCKS) * 256 + tid;
            if (e < N_EDGES) rank[e] = atomicAdd(&cnts[dst[e]], 1);
        }
        return;
    }

    const int w    = tid >> 6;
    const int l    = tid & 63;
    const int lrow = l & 15;
    const int lq   = l >> 4;

    const bool isSelf = (w >= 2);
    const float* W = isSelf ? W_self : W_ne;   // rows [0,128) of W_ne == W1
    const int colw = (w & 1) * 64;
    u16* Y = isSelf ? HS : H1;

    bf16x8 Wf[4][4];
#pragma unroll
    for (int mt = 0; mt < 4; ++mt) {
        const int c = colw + mt * 16 + lrow;
#pragma unroll
        for (int kk = 0; kk < 4; ++kk) {
            float tmp[8];
#pragma unroll
            for (int t = 0; t < 8; ++t) tmp[t] = W[(kk * 32 + lq * 8 + t) * 128 + c];
            Wf[mt][kk] = pack8(tmp);
        }
    }
    float4 bias4[4];
#pragma unroll
    for (int mt = 0; mt < 4; ++mt) {
        if (isSelf) bias4[mt] = *(const float4*)(b_self + colw + mt * 16 + lq * 4);
        else { bias4[mt].x = 0.f; bias4[mt].y = 0.f; bias4[mt].z = 0.f; bias4[mt].w = 0.f; }
    }

    const int srow = tid >> 1;
    const int skc  = (tid & 1) * 8;
    const int r0 = bid * 128;
    {
        const int gr = min(r0 + srow, N_NODES - 1);
        const float4* np = (const float4*)(nfeat + (size_t)gr * 128 + skc * 8);
        const int swz = (srow & 7);
#pragma unroll
        for (int j = 0; j < 8; ++j) {
            float4 x = np[2 * j], y = np[2 * j + 1];
            float tmp[8] = {x.x, x.y, x.z, x.w, y.x, y.y, y.z, y.w};
            bf16x8 f = pack8(tmp);
            const int kc = skc + j;
            *(bf16x8*)(Nb + srow * 256 + (((kc) ^ swz) * 16)) = f;
        }
    }
    __syncthreads();

    f32x4 acc[4][8];
#pragma unroll
    for (int mt = 0; mt < 4; ++mt)
#pragma unroll
        for (int nt = 0; nt < 8; ++nt) {
            acc[mt][nt][0] = bias4[mt].x; acc[mt][nt][1] = bias4[mt].y;
            acc[mt][nt][2] = bias4[mt].z; acc[mt][nt][3] = bias4[mt].w;
        }
#pragma unroll
    for (int nt = 0; nt < 8; ++nt) {
        const int r = nt * 16 + lrow;
        const int swz = (r & 7);
        bf16x8 Be[4];
#pragma unroll
        for (int kk = 0; kk < 4; ++kk)
            Be[kk] = *(const bf16x8*)(Nb + r * 256 + (((kk * 4 + lq) ^ swz) * 16));
#pragma unroll
        for (int mt = 0; mt < 4; ++mt)
#pragma unroll
            for (int kk = 0; kk < 4; ++kk)
                acc[mt][nt] = __builtin_amdgcn_mfma_f32_16x16x32_bf16(Wf[mt][kk], Be[kk], acc[mt][nt], 0, 0, 0);
    }

#pragma unroll
    for (int nt = 0; nt < 8; ++nt) {
        const int n = r0 + nt * 16 + lrow;
        if (n < N_NODES) {
#pragma unroll
            for (int mt = 0; mt < 4; ++mt) {
                const int c0 = colw + mt * 16 + lq * 4;
                ushort4 o;
                o.x = f2bf(acc[mt][nt][0]); o.y = f2bf(acc[mt][nt][1]);
                o.z = f2bf(acc[mt][nt][2]); o.w = f2bf(acc[mt][nt][3]);
                *(ushort4*)(Y + (size_t)n * 128 + c0) = o;
            }
        }
    }
}

// ---------------------------------------------------------------------------
#define SCAN_T 1024
#define SCAN_CHUNK 49
__global__ void scan_kernel(const int* __restrict__ counts, int* __restrict__ off) {
    __shared__ int part[SCAN_T];
    const int t = threadIdx.x;
    const int base = t * SCAN_CHUNK;
    int s = 0;
    for (int k = 0; k < SCAN_CHUNK; ++k) {
        const int i = base + k;
        if (i < N_NODES) s += counts[i];
    }
    part[t] = s;
    __syncthreads();
    for (int d = 1; d < SCAN_T; d <<= 1) {
        int v = (t >= d) ? part[t - d] : 0;
        __syncthreads();
        part[t] += v;
        __syncthreads();
    }
    int excl = part[t] - s;
    for (int k = 0; k < SCAN_CHUNK; ++k) {
        const int i = base + k;
        if (i < N_NODES) { off[i] = excl; excl += counts[i]; }
    }
    if (t == SCAN_T - 1) off[N_NODES] = excl;
}

// ---------------------------------------------------------------------------
// Edge GEMM v4: 128-B-segment random traffic (R12) + conflict-free HMb
// (272-B row stride, consecutive-row group ownership) + sT race fix (regs).
// ---------------------------------------------------------------------------
__global__ __launch_bounds__(256, 3) void edge_gemm_scatter_kernel(
    const float* __restrict__ efeat, const int* __restrict__ src,
    const int* __restrict__ dst, const int* __restrict__ rank,
    const int* __restrict__ offs, const float* __restrict__ W2fT,
    const float* __restrict__ b_ne, const u16* __restrict__ H1,
    u16* __restrict__ mbuf) {

    __shared__ __align__(16) char Ab[128 * 64 * 2];    // 16 KB A-tile
    __shared__ __align__(16) char HMb[128 * HROW];     // 34 KB H1/m tile (padded rows)
    __shared__ int sS[128];
    __shared__ int sT[128];

    const int tid  = threadIdx.x;
    const int w    = tid >> 6;
    const int l    = tid & 63;
    const int lrow = l & 15;
    const int lq   = l >> 4;
    const int g    = tid >> 4;     // 16-lane group id (0..15); owns rows k*16+g
    const int gi   = tid & 15;     // lane within group

    bf16x8 Wf[2][2];
    float4 bias4[2];
#pragma unroll
    for (int mt = 0; mt < 2; ++mt) {
        const int c = w * 32 + mt * 16 + lrow;
#pragma unroll
        for (int kk = 0; kk < 2; ++kk) {
            const float* wp = W2fT + c * 64 + kk * 32 + lq * 8;
            float tmp[8];
#pragma unroll
            for (int j = 0; j < 8; ++j) tmp[j] = wp[j];
            Wf[mt][kk] = pack8(tmp);
        }
        bias4[mt] = *(const float4*)(b_ne + w * 32 + mt * 16 + lq * 4);
    }

    const int srow = tid >> 1;
    const int skh  = (tid & 1) * 32;   // k-half in floats

    for (int tile = blockIdx.x; tile < NTILES; tile += gridDim.x) {
        const int e0 = tile * 128;

        if (tid < 128) {
            const int e = e0 + tid;
            sS[tid] = src[e];
            sT[tid] = offs[dst[e]] + rank[e];
        }
        // ---- stage efeat rows (sequential) -> bf16 swizzled LDS
        {
            const float4* ep = (const float4*)(efeat + (size_t)(e0 + srow) * 64 + skh);
            const int swz = (srow & 7) << 4;
#pragma unroll
            for (int j = 0; j < 4; ++j) {
                float4 x = ep[2 * j], y = ep[2 * j + 1];
                float tmp[8] = {x.x, x.y, x.z, x.w, y.x, y.y, y.z, y.w};
                bf16x8 f = pack8(tmp);
                *(bf16x8*)(Ab + ((srow * 128 + skh * 2 + j * 16) ^ swz)) = f;
            }
        }
        __syncthreads();   // B1: Ab, sS, sT ready; prev-tile HMb consumers done

        // ---- snapshot scatter slots (race fix: reads 2 barriers ahead of overwrite)
        int str[8];
#pragma unroll
        for (int k = 0; k < 8; ++k) str[k] = sT[k * 16 + g];

        // ---- issue H1 gather (256B-contiguous per row; latency hides under MFMA)
        bf16x8 hreg[8];
#pragma unroll
        for (int k = 0; k < 8; ++k) {
            const int r = k * 16 + g;
            hreg[k] = *(const bf16x8*)(H1 + (size_t)sS[r] * 128 + gi * 8);
        }

        // ---- MFMA: D[out-col][edge] = W2f^T . efeat^T
        f32x4 acc[2][8];
#pragma unroll
        for (int mt = 0; mt < 2; ++mt)
#pragma unroll
            for (int nt = 0; nt < 8; ++nt) {
                acc[mt][nt][0] = bias4[mt].x; acc[mt][nt][1] = bias4[mt].y;
                acc[mt][nt][2] = bias4[mt].z; acc[mt][nt][3] = bias4[mt].w;
            }
#pragma unroll
        for (int nt = 0; nt < 8; ++nt) {
            const int r = nt * 16 + lrow;
            const int swz = (r & 7) << 4;
            bf16x8 Be0 = *(const bf16x8*)(Ab + ((r * 128 + lq * 16) ^ swz));
            bf16x8 Be1 = *(const bf16x8*)(Ab + ((r * 128 + 64 + lq * 16) ^ swz));
#pragma unroll
            for (int mt = 0; mt < 2; ++mt) {
                acc[mt][nt] = __builtin_amdgcn_mfma_f32_16x16x32_bf16(Wf[mt][0], Be0, acc[mt][nt], 0, 0, 0);
                acc[mt][nt] = __builtin_amdgcn_mfma_f32_16x16x32_bf16(Wf[mt][1], Be1, acc[mt][nt], 0, 0, 0);
            }
        }

        // ---- park gathered H1 rows (row stride 272B -> 4-bank phase step)
#pragma unroll
        for (int k = 0; k < 8; ++k) {
            const int r = k * 16 + g;
            *(bf16x8*)(HMb + r * HROW + gi * 16) = hreg[k];
        }
        __syncthreads();   // B2: HMb holds H1 rows

        // ---- epilogue: v = relu(acc + H1) written back in place
#pragma unroll
        for (int nt = 0; nt < 8; ++nt) {
            const int e = nt * 16 + lrow;
#pragma unroll
            for (int mt = 0; mt < 2; ++mt) {
                const int c0 = w * 32 + mt * 16 + lq * 4;
                const int byte = e * HROW + c0 * 2;
                ushort4 h4 = *(const ushort4*)(HMb + byte);
                ushort4 o;
                o.x = f2bf(fmaxf(acc[mt][nt][0] + bf2f(h4.x), 0.0f));
                o.y = f2bf(fmaxf(acc[mt][nt][1] + bf2f(h4.y), 0.0f));
                o.z = f2bf(fmaxf(acc[mt][nt][2] + bf2f(h4.z), 0.0f));
                o.w = f2bf(fmaxf(acc[mt][nt][3] + bf2f(h4.w), 0.0f));
                *(ushort4*)(HMb + byte) = o;
            }
        }
        __syncthreads();   // B3: HMb holds m rows

        // ---- coalesced scatter: 16-lane groups write 256B-contiguous rows
#pragma unroll
        for (int k = 0; k < 8; ++k) {
            const int r = k * 16 + g;
            bf16x8 v = *(const bf16x8*)(HMb + r * HROW + gi * 16);
            *(bf16x8*)(mbuf + (size_t)str[k] * 128 + gi * 8) = v;
        }
        // B1 of next iteration protects HMb/sS/sT reuse
    }
}

// ---------------------------------------------------------------------------
// Reduce v3 (R14-verified): 16-lane group per node, whole-row reads, no
// cross-lane reduce, 512B coalesced store.
// ---------------------------------------------------------------------------
__global__ __launch_bounds__(256, 4) void reduce_kernel(
    const int* __restrict__ off, const u16* __restrict__ mbuf,
    const u16* __restrict__ HS, float* __restrict__ out) {
    const int n  = (blockIdx.x * blockDim.x + threadIdx.x) >> 4;  // group = node
    if (n >= N_NODES) return;
    const int gi = threadIdx.x & 15;
    const int s0 = off[n], s1 = off[n + 1];

    float facc[8];
#pragma unroll
    for (int i = 0; i < 8; ++i) facc[i] = 0.0f;

    int s = s0;
    for (; s + 4 <= s1; s += 4) {
        bf16x8 v0 = *(const bf16x8*)(mbuf + (size_t)(s + 0) * 128 + gi * 8);
        bf16x8 v1 = *(const bf16x8*)(mbuf + (size_t)(s + 1) * 128 + gi * 8);
        bf16x8 v2 = *(const bf16x8*)(mbuf + (size_t)(s + 2) * 128 + gi * 8);
        bf16x8 v3 = *(const bf16x8*)(mbuf + (size_t)(s + 3) * 128 + gi * 8);
#pragma unroll
        for (int i = 0; i < 8; ++i)
            facc[i] += (bf2f((u16)v0[i]) + bf2f((u16)v1[i])) +
                       (bf2f((u16)v2[i]) + bf2f((u16)v3[i]));
    }
    for (; s < s1; ++s) {
        bf16x8 v = *(const bf16x8*)(mbuf + (size_t)s * 128 + gi * 8);
#pragma unroll
        for (int i = 0; i < 8; ++i) facc[i] += bf2f((u16)v[i]);
    }

    const int c = s1 - s0;
    const float inv = (c > 0) ? 1.0f / (float)c : 0.0f;
    bf16x8 hs = *(const bf16x8*)(HS + (size_t)n * 128 + gi * 8);
    float* op = out + (size_t)n * 128 + gi * 8;
    float4 o0, o1;
    o0.x = facc[0] * inv + bf2f((u16)hs[0]);
    o0.y = facc[1] * inv + bf2f((u16)hs[1]);
    o0.z = facc[2] * inv + bf2f((u16)hs[2]);
    o0.w = facc[3] * inv + bf2f((u16)hs[3]);
    o1.x = facc[4] * inv + bf2f((u16)hs[4]);
    o1.y = facc[5] * inv + bf2f((u16)hs[5]);
    o1.z = facc[6] * inv + bf2f((u16)hs[6]);
    o1.w = facc[7] * inv + bf2f((u16)hs[7]);
    *(float4*)op = o0;
    *(float4*)(op + 4) = o1;
}

// ---------------------------------------------------------------------------
extern "C" void kernel_launch(void* const* d_in, const int* in_sizes, int n_in,
                              void* d_out, int out_size, void* d_ws, size_t ws_size,
                              hipStream_t stream) {
    const float* nfeat  = (const float*)d_in[0];
    const float* efeat  = (const float*)d_in[1];
    const int*   src    = (const int*)d_in[2];
    const int*   dst    = (const int*)d_in[3];
    const float* W_edge = (const float*)d_in[4];
    const float* W_ne   = (const float*)d_in[5];
    const float* b_ne   = (const float*)d_in[6];
    const float* W_self = (const float*)d_in[7];
    const float* b_self = (const float*)d_in[8];

    float* out = (float*)d_out;
    char* ws = (char*)d_ws;

    // ws layout (~234.1 MB; >=237 MB proven available)
    const size_t OFF_W2   = 0;          // 32768 B
    const size_t OFF_CNT  = 32768;      // 200000 B (+pad)
    const size_t OFF_OFFS = 232960;     // 200064 B (+pad)
    const size_t OFF_RANK = 433152;     // 3.2 MB
    const size_t OFF_H1   = 3633152;    // 12.8 MB
    const size_t OFF_HS   = 16433152;   // 12.8 MB
    const size_t OFF_M    = 29233152;   // 204.8 MB -> end 234033152

    float* W2fT = (float*)(ws + OFF_W2);
    int*   cnts = (int*)(ws + OFF_CNT);
    int*   offs = (int*)(ws + OFF_OFFS);
    int*   rank = (int*)(ws + OFF_RANK);
    u16*   H1   = (u16*)(ws + OFF_H1);
    u16*   HS   = (u16*)(ws + OFF_HS);
    u16*   mbuf = (u16*)(ws + OFF_M);

    hipMemsetAsync(cnts, 0, N_NODES * sizeof(int), stream);
    prep_kernel<<<NODE_TILES + W2_BLOCKS + CNT_BLOCKS, 256, 0, stream>>>(
        nfeat, W_ne, W_self, b_self, W_edge, dst, H1, HS, W2fT, cnts, rank);
    scan_kernel<<<1, SCAN_T, 0, stream>>>(cnts, offs);
    edge_gemm_scatter_kernel<<<2048, 256, 0, stream>>>(
        efeat, src, dst, rank, offs, W2fT, b_ne, H1, mbuf);
    reduce_kernel<<<(N_NODES * 16 + 255) / 256, 256, 0, stream>>>(offs, mbuf, HS, out);
}